// Round 1
// baseline (2365.060 us; speedup 1.0000x reference)
//
#include <hip/hip_runtime.h>
#include <math.h>

#define N_ATOMS 20000
#define M 12
#define B 41
#define ORIG 92
#define F 64
#define D 169        // 2F + B
#define DPAD 172     // D padded so LDS rows are 16B-aligned
#define NCONV 3
#define K 3
#define TWOK 6
#define H 128
#define N0 400
#define EPS 1e-5f
#define KD (K * D)   // 507

// ---------------- embedding: x = atom_fea @ emb_w + emb_b ----------------
__global__ void emb_kernel(const float* __restrict__ atom_fea,
                           const float* __restrict__ emb_w,
                           const float* __restrict__ emb_b,
                           float* __restrict__ x) {
    int i = blockIdx.x * blockDim.x + threadIdx.x;
    if (i >= N_ATOMS * F) return;
    int n = i / F, f = i % F;
    const float* a = atom_fea + n * ORIG;
    float acc = emb_b[f];
    #pragma unroll 4
    for (int d = 0; d < ORIG; ++d)
        acc = fmaf(a[d], emb_w[d * F + f], acc);
    x[i] = acc;
}

// ---------------- fused conv layer: one block per atom ----------------
__global__ __launch_bounds__(256, 4)
void conv_kernel(const float* __restrict__ xin,
                 const float* __restrict__ nbrin,
                 const int* __restrict__ idx,
                 const float* __restrict__ fc_w,   // (K,D,D)
                 const float* __restrict__ fc_b,   // (K,D)
                 const float* __restrict__ bn1_g,
                 const float* __restrict__ bn1_b,
                 const float* __restrict__ bn1_m,
                 const float* __restrict__ bn1_v,  // (K,D)
                 const float* __restrict__ bn2_g,
                 const float* __restrict__ bn2_b,
                 const float* __restrict__ bn2_m,
                 const float* __restrict__ bn2_v,  // (K,F)
                 const float* __restrict__ atom_w, // (K,2K)
                 const float* __restrict__ atom_b, // (2K)
                 const float* __restrict__ nbr_w,  // (K,2K)
                 const float* __restrict__ nbr_b,  // (2K)
                 float* __restrict__ xout,
                 float* __restrict__ nbrout) {
    __shared__ __align__(16) float s_total[M][DPAD];  // 8256 B
    __shared__ float s_filt[K][M][F];                 // 9216 B
    __shared__ float s_core[K][M][F];                 // 9216 B
    __shared__ float s_nnk[K][M][B];                  // 5904 B
    __shared__ float s_outk[K][F];                    // 768 B

    const int n = blockIdx.x;
    const int t = threadIdx.x;

    // stage total = [self(F) | gathered(F) | nbr(B)] for all M neighbors
    for (int i = t; i < M * D; i += 256) {
        int m = i / D, d = i % D;
        float v;
        if (d < F)            v = xin[n * F + d];
        else if (d < 2 * F)   v = xin[idx[n * M + m] * F + (d - F)];
        else                  v = nbrin[(n * M + m) * B + (d - 2 * F)];
        s_total[m][d] = v;
    }
    __syncthreads();

    // each thread owns columns t and t+256 of the K*D=507 outputs,
    // accumulating all M rows at once
    float acc[2][M];
    #pragma unroll
    for (int cc = 0; cc < 2; ++cc)
        #pragma unroll
        for (int m = 0; m < M; ++m) acc[cc][m] = 0.f;

    const int cols[2] = {t, t + 256};
    const float* wp[2];
    #pragma unroll
    for (int cc = 0; cc < 2; ++cc) {
        int c = (cols[cc] < KD) ? cols[cc] : 0;
        wp[cc] = fc_w + (c / D) * D * D + (c % D);   // stride D per d
    }

    for (int d4 = 0; d4 < D / 4; ++d4) {             // 42 groups of 4
        const int d = d4 * 4;
        float w[2][4];
        #pragma unroll
        for (int cc = 0; cc < 2; ++cc)
            #pragma unroll
            for (int q = 0; q < 4; ++q)
                w[cc][q] = wp[cc][(d + q) * D];
        #pragma unroll
        for (int m = 0; m < M; ++m) {
            float4 tv = *reinterpret_cast<const float4*>(&s_total[m][d]);
            #pragma unroll
            for (int cc = 0; cc < 2; ++cc) {
                acc[cc][m] = fmaf(tv.x, w[cc][0], acc[cc][m]);
                acc[cc][m] = fmaf(tv.y, w[cc][1], acc[cc][m]);
                acc[cc][m] = fmaf(tv.z, w[cc][2], acc[cc][m]);
                acc[cc][m] = fmaf(tv.w, w[cc][3], acc[cc][m]);
            }
        }
    }
    {   // remainder d = 168
        const int d = 168;
        float w[2];
        #pragma unroll
        for (int cc = 0; cc < 2; ++cc) w[cc] = wp[cc][d * D];
        #pragma unroll
        for (int m = 0; m < M; ++m) {
            float tv = s_total[m][d];
            #pragma unroll
            for (int cc = 0; cc < 2; ++cc)
                acc[cc][m] = fmaf(tv, w[cc], acc[cc][m]);
        }
    }

    // per-column epilogue: bias + bn1, then route by e
    #pragma unroll
    for (int cc = 0; cc < 2; ++cc) {
        int c = cols[cc];
        if (c < KD) {
            int k = c / D, e = c % D;
            float scale = bn1_g[k * D + e] * rsqrtf(bn1_v[k * D + e] + EPS);
            float shift = bn1_b[k * D + e] - bn1_m[k * D + e] * scale;
            float bias  = fc_b[k * D + e];
            float v[M];
            #pragma unroll
            for (int m = 0; m < M; ++m)
                v[m] = fmaf(acc[cc][m] + bias, scale, shift);
            if (e < F) {
                // softmax over neighbors M (all in this thread)
                float mx = v[0];
                #pragma unroll
                for (int m = 1; m < M; ++m) mx = fmaxf(mx, v[m]);
                float s = 0.f;
                #pragma unroll
                for (int m = 0; m < M; ++m) { v[m] = expf(v[m] - mx); s += v[m]; }
                float inv = 1.f / s;
                #pragma unroll
                for (int m = 0; m < M; ++m) s_filt[k][m][e] = v[m] * inv;
            } else if (e < 2 * F) {
                #pragma unroll
                for (int m = 0; m < M; ++m) s_core[k][m][e - F] = fmaxf(v[m], 0.f);
            } else {
                #pragma unroll
                for (int m = 0; m < M; ++m)
                    s_nnk[k][m][e - 2 * F] = v[m] + s_total[m][e];  // bond residual
            }
        }
    }
    __syncthreads();

    // summed = sum_m filt*core, bn2, atom residual -> s_outk[k][f]
    if (t < K * F) {
        int k = t / F, f = t % F;
        float s = 0.f;
        #pragma unroll
        for (int m = 0; m < M; ++m)
            s = fmaf(s_filt[k][m][f], s_core[k][m][f], s);
        float scale = bn2_g[k * F + f] * rsqrtf(bn2_v[k * F + f] + EPS);
        float shift = bn2_b[k * F + f] - bn2_m[k * F + f] * scale;
        s_outk[k][f] = s_total[0][f] + fmaf(s, scale, shift);
    }
    __syncthreads();

    // atom gate: og = outk @ atom_w + atom_b; out = sum_j og[:K]*softmax(og[K:])
    if (t < F) {
        int f = t;
        float og[TWOK];
        #pragma unroll
        for (int j = 0; j < TWOK; ++j) {
            float a = atom_b[j];
            #pragma unroll
            for (int k = 0; k < K; ++k)
                a = fmaf(s_outk[k][f], atom_w[k * TWOK + j], a);
            og[j] = a;
        }
        float mx = fmaxf(fmaxf(og[K], og[K + 1]), og[K + 2]);
        float e0 = expf(og[K] - mx), e1 = expf(og[K + 1] - mx), e2 = expf(og[K + 2] - mx);
        float inv = 1.f / (e0 + e1 + e2);
        xout[n * F + f] = (og[0] * e0 + og[1] * e1 + og[2] * e2) * inv;
    }

    // bond gate: ng = nnk @ nbr_w + nbr_b per (m,b)
    for (int i = t; i < M * B; i += 256) {
        int m = i / B, b = i % B;
        float ng[TWOK];
        #pragma unroll
        for (int j = 0; j < TWOK; ++j) {
            float a = nbr_b[j];
            #pragma unroll
            for (int k = 0; k < K; ++k)
                a = fmaf(s_nnk[k][m][b], nbr_w[k * TWOK + j], a);
            ng[j] = a;
        }
        float mx = fmaxf(fmaxf(ng[K], ng[K + 1]), ng[K + 2]);
        float e0 = expf(ng[K] - mx), e1 = expf(ng[K + 1] - mx), e2 = expf(ng[K + 2] - mx);
        float inv = 1.f / (e0 + e1 + e2);
        nbrout[(n * M + m) * B + b] = (ng[0] * e0 + ng[1] * e1 + ng[2] * e2) * inv;
    }
}

// ---------------- pooling: segment sums via atomics ----------------
__global__ void pool_kernel(const float* __restrict__ x,
                            const int* __restrict__ cidx,
                            float* __restrict__ sums,
                            float* __restrict__ cnt) {
    int i = blockIdx.x * blockDim.x + threadIdx.x;
    if (i >= N_ATOMS * F) return;
    int n = i / F, f = i % F;
    int c = cidx[n];
    atomicAdd(&sums[c * F + f], x[i]);
    if (f == 0) atomicAdd(&cnt[c], 1.0f);
}

// ---------------- head: mean -> relu -> fc1 -> relu -> out ----------------
__global__ void head_kernel(const float* __restrict__ sums,
                            const float* __restrict__ cnt,
                            const float* __restrict__ fc1_w,
                            const float* __restrict__ fc1_b,
                            const float* __restrict__ out_w,
                            const float* __restrict__ out_b,
                            float* __restrict__ out) {
    const int c = blockIdx.x;
    const int t = threadIdx.x;  // 128 threads
    __shared__ float a[F];
    __shared__ float red[H];
    float inv_cnt = 1.f / fmaxf(cnt[c], 1.0f);
    if (t < F) a[t] = fmaxf(sums[c * F + t] * inv_cnt, 0.f);
    __syncthreads();
    float hv = fc1_b[t];
    #pragma unroll 4
    for (int f = 0; f < F; ++f)
        hv = fmaf(a[f], fc1_w[f * H + t], hv);
    hv = fmaxf(hv, 0.f);
    red[t] = hv * out_w[t];
    __syncthreads();
    for (int s = H / 2; s > 0; s >>= 1) {
        if (t < s) red[t] += red[t + s];
        __syncthreads();
    }
    if (t == 0) out[c] = red[0] + out_b[0];
}

extern "C" void kernel_launch(void* const* d_in, const int* in_sizes, int n_in,
                              void* d_out, int out_size, void* d_ws, size_t ws_size,
                              hipStream_t stream) {
    (void)in_sizes; (void)n_in; (void)out_size; (void)ws_size;
    const float* atom_fea = (const float*)d_in[0];
    const float* nbr_fea  = (const float*)d_in[1];
    const int*   nbr_idx  = (const int*)d_in[2];
    const int*   cidx     = (const int*)d_in[3];
    // d_in[4] = n_crystals (fixed 400)
    const float* emb_w = (const float*)d_in[5];
    const float* emb_b = (const float*)d_in[6];
    const float* fc_w  = (const float*)d_in[7];
    const float* fc_b  = (const float*)d_in[8];
    const float* bn1_g = (const float*)d_in[9];
    const float* bn1_b = (const float*)d_in[10];
    const float* bn1_m = (const float*)d_in[11];
    const float* bn1_v = (const float*)d_in[12];
    const float* bn2_g = (const float*)d_in[13];
    const float* bn2_b = (const float*)d_in[14];
    const float* bn2_m = (const float*)d_in[15];
    const float* bn2_v = (const float*)d_in[16];
    const float* atom_w = (const float*)d_in[17];
    const float* atom_b = (const float*)d_in[18];
    const float* nbr_w  = (const float*)d_in[19];
    const float* nbr_b  = (const float*)d_in[20];
    const float* fc1_w  = (const float*)d_in[21];
    const float* fc1_b  = (const float*)d_in[22];
    const float* out_w  = (const float*)d_in[23];
    const float* out_b  = (const float*)d_in[24];
    float* out = (float*)d_out;

    float* xA   = (float*)d_ws;                    // N*F
    float* xB   = xA + (size_t)N_ATOMS * F;        // N*F
    float* nbrA = xB + (size_t)N_ATOMS * F;        // N*M*B
    float* nbrB = nbrA + (size_t)N_ATOMS * M * B;  // N*M*B
    float* sums = nbrB + (size_t)N_ATOMS * M * B;  // N0*F
    float* cnt  = sums + (size_t)N0 * F;           // N0

    emb_kernel<<<(N_ATOMS * F + 255) / 256, 256, 0, stream>>>(atom_fea, emb_w, emb_b, xA);

    const float* xs_in[NCONV]  = {xA, xB, xA};
    float*       xs_out[NCONV] = {xB, xA, xB};
    const float* nb_in[NCONV]  = {nbr_fea, nbrA, nbrB};
    float*       nb_out[NCONV] = {nbrA, nbrB, nbrA};
    for (int i = 0; i < NCONV; ++i) {
        conv_kernel<<<N_ATOMS, 256, 0, stream>>>(
            xs_in[i], nb_in[i], nbr_idx,
            fc_w + (size_t)i * K * D * D, fc_b + (size_t)i * K * D,
            bn1_g + (size_t)i * K * D, bn1_b + (size_t)i * K * D,
            bn1_m + (size_t)i * K * D, bn1_v + (size_t)i * K * D,
            bn2_g + (size_t)i * K * F, bn2_b + (size_t)i * K * F,
            bn2_m + (size_t)i * K * F, bn2_v + (size_t)i * K * F,
            atom_w + (size_t)i * K * TWOK, atom_b + (size_t)i * TWOK,
            nbr_w + (size_t)i * K * TWOK, nbr_b + (size_t)i * TWOK,
            xs_out[i], nb_out[i]);
    }

    hipMemsetAsync(sums, 0, (size_t)(N0 * F + N0) * sizeof(float), stream);
    pool_kernel<<<(N_ATOMS * F + 255) / 256, 256, 0, stream>>>(xB, cidx, sums, cnt);
    head_kernel<<<N0, H, 0, stream>>>(sums, cnt, fc1_w, fc1_b, out_w, out_b, out);
}